// Round 5
// baseline (691.034 us; speedup 1.0000x reference)
//
#include <hip/hip_runtime.h>
#include <math.h>

#define HIDDEN 16
#define CIN 5
#define BB 8
#define TT 12
#define HH 256
#define WW 256
// legacy (per-step fallback) tile geometry
#define TX 32
#define TY 8
#define HALO_X 34
#define HALO_Y 10
#define NPX (HALO_X * HALO_Y)
#define STRIDE 40
// persistent tile geometry: 64x8, one tile per block
#define PTX 64
#define PTY 8
#define PHX 66
#define PHY 10
#define PNPX (PHX * PHY)        // 660 staged pixels
#define PRING 148               // staged perimeter: 2*66 + 2*8
#define ROWSH 24                // shorts per staged px: h[16] | x[8] (48 B)
#define ZOFFP (PNPX * ROWSH)    // zero-pad row (shorts)
#define NBLK_PERSIST 1024       // 4 blocks/CU x 256 CU, 1 tile each
#define XSTEP (HH * WW * 8)     // xp shorts per t-slice per batch

typedef __attribute__((ext_vector_type(8))) short bf16x8;   // 8 bf16 (4 VGPRs)
typedef __attribute__((ext_vector_type(4))) float floatx4;

__device__ __forceinline__ unsigned short f2bf(float f) {   // RNE fp32->bf16
    unsigned int u = __float_as_uint(f);
    u += 0x7fffu + ((u >> 16) & 1u);
    return (unsigned short)(u >> 16);
}
__device__ __forceinline__ float bf2f(unsigned short s) {
    return __uint_as_float(((unsigned int)s) << 16);
}
__device__ __forceinline__ float rcpf(float x) {            // v_rcp_f32 (~1 ulp)
    float r;
    asm("v_rcp_f32 %0, %1" : "=v"(r) : "v"(x));
    return r;
}
__device__ __forceinline__ float fast_sigmoid(float x) {
    return rcpf(1.0f + __expf(-x));
}
__device__ __forceinline__ float fast_tanh(float x) {
    float e2 = __expf(-2.0f * fabsf(x));
    float t = (1.0f - e2) * rcpf(1.0f + e2);
    return copysignf(t, x);
}
// legacy-path gates (div-based, proven)
__device__ __forceinline__ float leg_sigmoid(float x) { return 1.0f / (1.0f + __expf(-x)); }
__device__ __forceinline__ float leg_tanh(float x) {
    float e2 = __expf(-2.0f * fabsf(x));
    float t = (1.0f - e2) / (1.0f + e2);
    return copysignf(t, x);
}

// Pack W_cell [64][21][3][3] into exact B-fragment layout for
// mfma_f32_16x16x32_bf16: Wfrag[tap][gate][lane][j]; lane holds
// B[k=(lane>>4)*8+j][col=lane&15], col = hidden unit, N-tile = gate.
// k-order: 0..15 = h units (ci_ref 5+k), 16..20 = x chans, 21..31 = 0.
__global__ void prep_w_kernel(const float* __restrict__ Wc,
                              unsigned short* __restrict__ Wfrag) {
    int i = blockIdx.x * 256 + threadIdx.x;
    if (i >= 9 * 4 * 64 * 8) return;
    int j    = i & 7;
    int lane = (i >> 3) & 63;
    int g    = (i >> 9) & 3;
    int tap  = i >> 11;
    int k    = ((lane >> 4) << 3) + j;
    int col  = lane & 15;
    int o    = g * 16 + col;
    float w  = 0.0f;
    if (k < 21) {
        int ci_ref = (k < 16) ? (5 + k) : (k - 16);
        w = Wc[(o * 21 + ci_ref) * 9 + tap];
    }
    Wfrag[i] = f2bf(w);
}

// One-time x repack: planar fp32 [b][t][c][y][x] -> channel-last bf16 [b][t][y][x][8]
__global__ void prep_x_kernel(const float* __restrict__ x,
                              unsigned short* __restrict__ xp) {
    size_t n = (size_t)blockIdx.x * 256 + threadIdx.x;
    const size_t TOTPX = (size_t)BB * TT * HH * WW;
    if (n >= TOTPX) return;
    size_t bt  = n / (size_t)(HH * WW);
    size_t pix = n - bt * (size_t)(HH * WW);
    const float* src = x + bt * (size_t)CIN * HH * WW + pix;
    unsigned short v[8];
    #pragma unroll
    for (int c = 0; c < CIN; ++c) v[c] = f2bf(src[(size_t)c * HH * WW]);
    v[5] = 0; v[6] = 0; v[7] = 0;
    *(uint4*)&xp[n * 8] = *(const uint4*)v;
}

__global__ void prep_flags_kernel(unsigned int* __restrict__ flags) {
    int i = blockIdx.x * 256 + threadIdx.x;
    if (i < NBLK_PERSIST) flags[i] = 0;
}

// ---------------------------------------------------------------------------
// Persistent kernel, ONE 64x8 tile per block (1024 blocks, 4/CU).
// h resident in LDS ([660][h16|x8]); only the 148-px staged ring is loaded
// from global and the 140-px interior boundary stored, per step. c in
// registers. Tile-flag protocol (as r3/r4). Final 1x1 conv fused at t==TT-1.
// Tile map XCD-chunked: tile_id = (bid&7)*128 + (bid>>3); batch = bid&7.
// Per-batch grid: 4 tiles in x, 32 in y.
// ---------------------------------------------------------------------------
__global__ __launch_bounds__(256, 4)
void convlstm_persistent_kernel(const float* __restrict__ x,
                                const unsigned short* __restrict__ xp,  // may be null
                                unsigned short* __restrict__ ha,
                                unsigned short* __restrict__ hbuf,
                                const unsigned short* __restrict__ Wfrag,
                                const float* __restrict__ bias,
                                const float* __restrict__ Wf,
                                const float* __restrict__ bfin,
                                float* __restrict__ out,
                                unsigned int* __restrict__ flags,
                                int use_xp) {
    __shared__ unsigned short hx[PNPX * ROWSH + 8];   // 31696 B

    const int tid  = threadIdx.x;
    const int lane = tid & 63;
    const int wave = tid >> 6;
    const int u    = lane & 15;
    const int quad = lane >> 4;
    const int bid  = (int)blockIdx.x;

    const int tile_id = (bid & 7) * 128 + (bid >> 3);
    const int tq  = tile_id & 127;
    const int tqx = tq & 3;
    const int tqy = tq >> 2;
    const int x0  = tqx * PTX;
    const int y0  = tqy * PTY;
    const int bb  = tile_id >> 7;          // == bid & 7

    // ---- neighbor ids (wave0 lanes 0..7 poll) ----
    int nb_id = 0;
    bool nb_act = false;
    {
        int s  = lane + (lane >= 4 ? 1 : 0);      // skip center
        int dy = s / 3 - 1;
        int dx = s - (s / 3) * 3 - 1;
        nb_act = (lane < 8) && (tqx + dx >= 0) && (tqx + dx < 4)
                            && (tqy + dy >= 0) && (tqy + dy < 32);
        nb_id = nb_act ? (tile_id + dy * 4 + dx) : 0;
    }

    // ---- x staging descriptors (staged rows tid, tid+256, tid+512) ----
    int xof0 = 0, xof1 = 0, xof2 = 0;
    int pix0 = 0, pix1 = 0, pix2 = 0;
    unsigned inbm = 0;
    #pragma unroll
    for (int it = 0; it < 3; ++it) {
        int i = tid + it * 256;
        if (it == 2 && tid >= PNPX - 512) break;
        int ly = i / PHX;
        int lx = i - ly * PHX;
        int gy = y0 + ly - 1;
        int gx = x0 + lx - 1;
        bool inb = (gy >= 0 && gy < HH && gx >= 0 && gx < WW);
        int pix = gy * WW + gx;
        int xo  = (bb * TT * HH * WW + pix) * 8;
        if (it == 0) { xof0 = xo; pix0 = pix; }
        else if (it == 1) { xof1 = xo; pix1 = pix; }
        else { xof2 = xo; pix2 = pix; }
        if (inb) inbm |= 1u << it;
    }

    // ---- ring descriptors (tid < 148) ----
    int rrow = 0, rgoff = 0;
    bool ring_inb = false;
    if (tid < PRING) {
        int ly, lx;
        if (tid < 66)       { ly = 0;              lx = tid; }
        else if (tid < 132) { ly = PHY - 1;        lx = tid - 66; }
        else { int k = tid - 132; ly = 1 + (k >> 1); lx = (k & 1) * (PHX - 1); }
        rrow = ly * PHX + lx;
        int gy = y0 + ly - 1;
        int gx = x0 + lx - 1;
        ring_inb = (gy >= 0 && gy < HH && gx >= 0 && gx < WW);
        rgoff = (bb * HH * WW + gy * WW + gx) * HIDDEN;
    }

    // ---- prologue: x prefetch for t=0 ----
    uint4 xr0 = {0, 0, 0, 0}, xr1 = {0, 0, 0, 0}, xr2 = {0, 0, 0, 0};
    if (use_xp) {
        if (inbm & 1u) xr0 = *(const uint4*)&xp[xof0];
        if (inbm & 2u) xr1 = *(const uint4*)&xp[xof1];
        if (tid < PNPX - 512 && (inbm & 4u)) xr2 = *(const uint4*)&xp[xof2];
    }

    // ---- init: zero h-part of the staged region + zero pad row ----
    for (int i = tid; i < PNPX; i += 256) {
        uint4 z = {0, 0, 0, 0};
        *(uint4*)&hx[i * ROWSH]     = z;
        *(uint4*)&hx[i * ROWSH + 8] = z;
    }
    if (tid == 0) { uint4 z = {0, 0, 0, 0}; *(uint4*)&hx[ZOFFP] = z; }

    float bg[4];
    #pragma unroll
    for (int g = 0; g < 4; ++g) bg[g] = bias[g * 16 + u];
    const float wfu = Wf[u];
    const float bf0 = bfin[0];

    // c-state: 4 quarters x [mh][r]; four named arrays, element-wise 4-way
    // select on runtime (h1,h2) -> cndmask chains, no runtime array indexing.
    float cQ0[2][4], cQ1[2][4], cQ2[2][4], cQ3[2][4];
    #pragma unroll
    for (int m = 0; m < 2; ++m)
        #pragma unroll
        for (int r = 0; r < 4; ++r) {
            cQ0[m][r] = 0.0f; cQ1[m][r] = 0.0f;
            cQ2[m][r] = 0.0f; cQ3[m][r] = 0.0f;
        }

    #pragma unroll 1
    for (int t = 0; t < TT; ++t) {
        const unsigned short* h_in  = (t & 1) ? ha : hbuf;
        unsigned short*       h_out = (t & 1) ? hbuf : ha;
        const int first = (t == 0);
        const int last  = (t == TT - 1);

        // ---- (A) wait for 8 neighbors to have completed step t-1 ----
        if (t > 0) {
            if (wave == 0) {
                const unsigned need = (unsigned)t;
                for (;;) {
                    unsigned v = nb_act
                        ? __hip_atomic_load(&flags[nb_id], __ATOMIC_RELAXED,
                                            __HIP_MEMORY_SCOPE_AGENT)
                        : 0xFFFFFFFFu;
                    if (__all(v >= need)) break;
                    __builtin_amdgcn_s_sleep(2);
                }
                if (tid == 0) __threadfence();   // acquire
            }
            __syncthreads();
        }

        // ---- (B) stage: x (prefetched) + h halo ring ----
        if (use_xp) {
            *(uint4*)&hx[tid * ROWSH + 16]         = xr0;
            *(uint4*)&hx[(tid + 256) * ROWSH + 16] = xr1;
            if (tid < PNPX - 512)
                *(uint4*)&hx[(tid + 512) * ROWSH + 16] = xr2;
        } else {
            #pragma unroll
            for (int it = 0; it < 3; ++it) {
                if (it == 2 && tid >= PNPX - 512) break;
                int pv = (it == 0) ? pix0 : (it == 1) ? pix1 : pix2;
                const bool inb = (inbm >> it) & 1;
                unsigned short v[8];
                #pragma unroll
                for (int ci = 0; ci < CIN; ++ci) {
                    float f = 0.0f;
                    if (inb) f = x[(((size_t)bb * TT + t) * CIN + ci) * (size_t)(HH * WW)
                                   + pv];
                    v[ci] = f2bf(f);
                }
                v[5] = 0; v[6] = 0; v[7] = 0;
                *(uint4*)&hx[(tid + it * 256) * ROWSH + 16] = *(const uint4*)v;
            }
        }
        if (!first && tid < PRING && ring_inb) {
            const unsigned short* hp = h_in + rgoff;
            *(uint4*)&hx[rrow * ROWSH]     = *(const uint4*)&hp[0];
            *(uint4*)&hx[rrow * ROWSH + 8] = *(const uint4*)&hp[8];
        }
        // issue x prefetch for step t+1
        if (use_xp && t + 1 < TT) {
            uint4 z4 = {0, 0, 0, 0};
            int ts = (t + 1) * XSTEP;
            xr0 = (inbm & 1u) ? *(const uint4*)&xp[xof0 + ts] : z4;
            xr1 = (inbm & 2u) ? *(const uint4*)&xp[xof1 + ts] : z4;
            if (tid < PNPX - 512)
                xr2 = (inbm & 4u) ? *(const uint4*)&xp[xof2 + ts] : z4;
        }
        __syncthreads();   // (C)

        // ---- (D) compute: 4 quarters (2x2 unroll-1), 2 M-strips each ----
        // strip m = wave + (qq*2+mh)*4: wave picks 16-col band, (qq,mh) row.
        #pragma unroll 1
        for (int h1 = 0; h1 < 2; ++h1) {
            #pragma unroll 1
            for (int h2 = 0; h2 < 2; ++h2) {
                const int qq = h1 * 2 + h2;
                floatx4 acc[2][4];
                int A[2];
                #pragma unroll
                for (int mh = 0; mh < 2; ++mh) {
                    int my = qq * 2 + mh;
                    int mx = wave << 4;
                    int bpx = my * PHX + mx + u;
                    A[mh] = (quad < 3) ? (bpx * ROWSH + quad * 8) : ZOFFP;
                    #pragma unroll
                    for (int g = 0; g < 4; ++g)
                        acc[mh][g] = (floatx4){bg[g], bg[g], bg[g], bg[g]};
                }
                const int msel = (quad < 3) ? ROWSH : 0;

                #pragma unroll 3
                for (int tap = 0; tap < 9; ++tap) {
                    int ky = tap / 3;
                    int kx = tap - ky * 3;
                    int ktap = ky * PHX + kx;
                    bf16x8 bfr[4];
                    #pragma unroll
                    for (int g = 0; g < 4; ++g)
                        bfr[g] = *(const bf16x8*)&Wfrag[(size_t)((tap * 4 + g) * 64 + lane) * 8];
                    #pragma unroll
                    for (int mh = 0; mh < 2; ++mh) {
                        bf16x8 af = *(const bf16x8*)&hx[A[mh] + ktap * msel];
                        #pragma unroll
                        for (int g = 0; g < 4; ++g)
                            acc[mh][g] = __builtin_amdgcn_mfma_f32_16x16x32_bf16(
                                af, bfr[g], acc[mh][g], 0, 0, 0);
                    }
                }

                // ---- epilogue ----
                #pragma unroll
                for (int mh = 0; mh < 2; ++mh) {
                    int my = qq * 2 + mh;
                    int py = y0 + my;
                    int col0 = (wave << 4) + quad * 4;
                    int eaddr = ((my + 1) * PHX + col0 + 1) * ROWSH + u;
                    size_t gidx0 = ((size_t)bb * HH * WW + (size_t)py * WW + x0 + col0)
                                   * HIDDEN + u;
                    bool topbot = (my == 0) || (my == PTY - 1);
                    #pragma unroll
                    for (int r = 0; r < 4; ++r) {
                        float ig = fast_sigmoid(acc[mh][0][r]);
                        float fg = fast_sigmoid(acc[mh][1][r]);
                        float og = fast_sigmoid(acc[mh][2][r]);
                        float gg = fast_tanh(acc[mh][3][r]);
                        float c_old = h1 ? (h2 ? cQ3[mh][r] : cQ2[mh][r])
                                         : (h2 ? cQ1[mh][r] : cQ0[mh][r]);
                        float c_new = fg * c_old + ig * gg;
                        if (h1) { if (h2) cQ3[mh][r] = c_new; else cQ2[mh][r] = c_new; }
                        else    { if (h2) cQ1[mh][r] = c_new; else cQ0[mh][r] = c_new; }
                        float hval = og * fast_tanh(c_new);
                        if (last) {
                            // fused 1x1 conv: sum over 16 channels (u lanes)
                            float s = wfu * hval;
                            s += __shfl_xor(s, 1);
                            s += __shfl_xor(s, 2);
                            s += __shfl_xor(s, 4);
                            s += __shfl_xor(s, 8);
                            if (u == 0)
                                out[(size_t)bb * HH * WW + (size_t)py * WW + x0 + col0 + r]
                                    = s + bf0;
                        } else {
                            unsigned short hs = f2bf(hval);
                            hx[eaddr + r * ROWSH] = hs;               // interior -> LDS
                            int col = col0 + r;
                            if (topbot || col == 0 || col == PTX - 1)
                                h_out[gidx0 + (size_t)r * HIDDEN] = hs; // ring -> global
                        }
                    }
                }
            }
        }

        // ---- (E) publish ----
        if (!last) {
            __syncthreads();   // drains vmcnt before barrier
            if (tid == 0) {
                __threadfence();   // release
                __hip_atomic_store(&flags[tile_id], (unsigned)(t + 1), __ATOMIC_RELAXED,
                                   __HIP_MEMORY_SCOPE_AGENT);
            }
        }
    }
}

// ---------------------------------------------------------------------------
// Legacy per-step path (round-0, proven) — fallback if cooperative launch
// is unavailable.
// ---------------------------------------------------------------------------
__global__ __launch_bounds__(256, 5)
void convlstm_step_kernel(const float* __restrict__ x, int t,
                          const unsigned short* __restrict__ xp,  // may be null
                          const unsigned short* __restrict__ h_in,
                          unsigned short* __restrict__ h_out,
                          float* __restrict__ c_state,
                          const unsigned short* __restrict__ Wfrag,
                          const float* __restrict__ bias,
                          int first, int use_xp) {
    __shared__ unsigned short tile[NPX * STRIDE];   // 27200 B

    const int tid  = threadIdx.x;
    const int lane = tid & 63;
    const int wave = tid >> 6;
    const int x0 = blockIdx.x * TX;
    const int y0 = blockIdx.y * TY;
    const int bb = blockIdx.z;

    for (int i = tid; i < NPX; i += 256) {
        int ly = i / HALO_X;
        int lx = i - ly * HALO_X;
        int gy = y0 + ly - 1;
        int gx = x0 + lx - 1;
        bool inb = (gy >= 0 && gy < HH && gx >= 0 && gx < WW);
        unsigned short* row = &tile[i * STRIDE];
        uint4 z = {0, 0, 0, 0};
        if (inb && !first) {
            size_t hbase = ((size_t)bb * HH * WW + (size_t)gy * WW + gx) * HIDDEN;
            *(uint4*)&row[0] = *(const uint4*)&h_in[hbase];
            *(uint4*)&row[8] = *(const uint4*)&h_in[hbase + 8];
        } else {
            *(uint4*)&row[0] = z;
            *(uint4*)&row[8] = z;
        }
        if (use_xp) {
            if (inb) {
                size_t xb = (((size_t)bb * TT + t) * (size_t)(HH * WW)
                             + (size_t)gy * WW + gx) * 8;
                *(uint4*)&row[16] = *(const uint4*)&xp[xb];
            } else {
                *(uint4*)&row[16] = z;
            }
        } else {
            #pragma unroll
            for (int ci = 0; ci < CIN; ++ci) {
                float v = 0.0f;
                if (inb) v = x[(((size_t)bb * TT + t) * CIN + ci) * (size_t)(HH * WW)
                               + (size_t)gy * WW + gx];
                row[16 + ci] = f2bf(v);
            }
            row[21] = 0; row[22] = 0; row[23] = 0;
        }
        *(uint4*)&row[24] = z;
    }
    __syncthreads();

    const int u    = lane & 15;
    const int quad = lane >> 4;

    float bg[4];
    #pragma unroll
    for (int g = 0; g < 4; ++g) bg[g] = bias[g * 16 + u];

    #pragma unroll 1
    for (int half = 0; half < 2; ++half) {
        floatx4 acc[2][4];
        int abase[2];
        #pragma unroll
        for (int mh = 0; mh < 2; ++mh) {
            int ml = half * 2 + mh;
            int m  = wave + ml * 4;
            int my = m >> 1;
            int mx = (m & 1) << 4;
            abase[mh] = (my * HALO_X + mx + u) * STRIDE + quad * 8;
            #pragma unroll
            for (int g = 0; g < 4; ++g)
                acc[mh][g] = (floatx4){bg[g], bg[g], bg[g], bg[g]};
        }

        #pragma unroll 3
        for (int tap = 0; tap < 9; ++tap) {
            int ky = tap / 3;
            int kx = tap - ky * 3;
            int toff = (ky * HALO_X + kx) * STRIDE;
            bf16x8 bfr[4];
            #pragma unroll
            for (int g = 0; g < 4; ++g)
                bfr[g] = *(const bf16x8*)&Wfrag[(size_t)((tap * 4 + g) * 64 + lane) * 8];
            #pragma unroll
            for (int mh = 0; mh < 2; ++mh) {
                bf16x8 af = *(const bf16x8*)&tile[abase[mh] + toff];
                #pragma unroll
                for (int g = 0; g < 4; ++g)
                    acc[mh][g] = __builtin_amdgcn_mfma_f32_16x16x32_bf16(
                        af, bfr[g], acc[mh][g], 0, 0, 0);
            }
        }

        #pragma unroll
        for (int mh = 0; mh < 2; ++mh) {
            int ml = half * 2 + mh;
            int m  = wave + ml * 4;
            int my = m >> 1;
            int mx = (m & 1) << 4;
            int py = y0 + my;
            #pragma unroll
            for (int r = 0; r < 4; ++r) {
                int pxx = x0 + mx + quad * 4 + r;
                size_t idx = ((size_t)bb * HH * WW + (size_t)py * WW + pxx) * HIDDEN + u;
                float ig = leg_sigmoid(acc[mh][0][r]);
                float fg = leg_sigmoid(acc[mh][1][r]);
                float og = leg_sigmoid(acc[mh][2][r]);
                float gg = leg_tanh(acc[mh][3][r]);
                float c_old = first ? 0.0f : c_state[idx];
                float c_new = fg * c_old + ig * gg;
                c_state[idx] = c_new;
                h_out[idx] = f2bf(og * leg_tanh(c_new));
            }
        }
    }
}

// Final 1x1 conv from bf16 channel-last h (legacy path only)
__global__ void final_conv_kernel(const unsigned short* __restrict__ h,
                                  const float* __restrict__ Wf,
                                  const float* __restrict__ bf_,
                                  float* __restrict__ out) {
    int i = blockIdx.x * 256 + threadIdx.x;
    if (i >= BB * HH * WW) return;
    size_t base = (size_t)i * HIDDEN;
    uint4 v0 = *(const uint4*)&h[base];
    uint4 v1 = *(const uint4*)&h[base + 8];
    const unsigned short* p0 = (const unsigned short*)&v0;
    const unsigned short* p1 = (const unsigned short*)&v1;
    float s = bf_[0];
    #pragma unroll
    for (int k = 0; k < 8; ++k) s += Wf[k] * bf2f(p0[k]);
    #pragma unroll
    for (int k = 0; k < 8; ++k) s += Wf[8 + k] * bf2f(p1[k]);
    out[i] = s;
}

extern "C" void kernel_launch(void* const* d_in, const int* in_sizes, int n_in,
                              void* d_out, int out_size, void* d_ws, size_t ws_size,
                              hipStream_t stream) {
    const float* x  = (const float*)d_in[0];
    const float* Wc = (const float*)d_in[1];
    const float* bc = (const float*)d_in[2];
    const float* Wf = (const float*)d_in[3];
    const float* bf = (const float*)d_in[4];
    float* out = (float*)d_out;

    char* ws = (char*)d_ws;
    const size_t h_bytes = (size_t)BB * HH * WW * HIDDEN * 2;   // 16.78 MB
    const size_t c_bytes = (size_t)BB * HH * WW * HIDDEN * 4;   // 33.55 MB
    const size_t w_bytes = 9 * 4 * 64 * 8 * 2;                  // 36.9 KB
    const size_t f_bytes = (size_t)NBLK_PERSIST * 4;            // 4 KB flags
    const size_t x_bytes = (size_t)BB * TT * HH * WW * 8 * 2;   // 100.7 MB

    unsigned short* h_a = (unsigned short*)(ws);
    unsigned short* h_b = (unsigned short*)(ws + h_bytes);
    float* c            = (float*)(ws + 2 * h_bytes);
    unsigned short* Wfr = (unsigned short*)(ws + 2 * h_bytes + c_bytes);
    unsigned int* flags = (unsigned int*)(ws + 2 * h_bytes + c_bytes + w_bytes);
    unsigned short* xp  = (unsigned short*)(ws + 2 * h_bytes + c_bytes + w_bytes + f_bytes);

    const int use_xp =
        (ws_size >= 2 * h_bytes + c_bytes + w_bytes + f_bytes + x_bytes) ? 1 : 0;

    prep_w_kernel<<<(9 * 4 * 64 * 8 + 255) / 256, 256, 0, stream>>>(Wc, Wfr);
    prep_flags_kernel<<<(NBLK_PERSIST + 255) / 256, 256, 0, stream>>>(flags);
    if (use_xp) {
        size_t totpx = (size_t)BB * TT * HH * WW;
        prep_x_kernel<<<(int)((totpx + 255) / 256), 256, 0, stream>>>(x, xp);
    }

    // Preferred path: persistent kernel (h in LDS, c in registers, 1 tile/blk).
    int occ = 0;
    hipOccupancyMaxActiveBlocksPerMultiprocessor(&occ, convlstm_persistent_kernel,
                                                 256, 0);
    bool done = false;
    if (occ >= 4) {
        const unsigned short* xp_arg = use_xp ? xp : (const unsigned short*)0;
        int use_xp_arg = use_xp;
        void* kargs[] = {
            (void*)&x, (void*)&xp_arg, (void*)&h_a, (void*)&h_b,
            (void*)&Wfr, (void*)&bc, (void*)&Wf, (void*)&bf,
            (void*)&out, (void*)&flags, (void*)&use_xp_arg
        };
        if (hipLaunchCooperativeKernel((const void*)convlstm_persistent_kernel,
                                       dim3(NBLK_PERSIST, 1, 1), dim3(256, 1, 1),
                                       kargs, 0, stream) == hipSuccess)
            done = true;
    }

    if (!done) {
        // Legacy per-step path (round-0 behavior)
        dim3 grid(WW / TX, HH / TY, BB);   // 2048 blocks
        dim3 block(256, 1, 1);
        const unsigned short* h_in = h_a;
        for (int t = 0; t < TT; ++t) {
            unsigned short* h_out = (t & 1) ? h_b : h_a;
            convlstm_step_kernel<<<grid, block, 0, stream>>>(
                x, t, use_xp ? xp : (const unsigned short*)0,
                h_in, h_out, c, Wfr, bc, (t == 0) ? 1 : 0, use_xp);
            h_in = h_out;
        }
        final_conv_kernel<<<(BB * HH * WW + 255) / 256, 256, 0, stream>>>(
            h_in, Wf, bf, out);
    }
}